// Round 1
// 252.324 us; speedup vs baseline: 1.0121x; 1.0121x over previous
//
#include <hip/hip_runtime.h>

#define N_ 16
#define C_ 128
#define HW_ 16384
#define K_ 1638   // int(0.1 * 16384)

typedef float nfloat4 __attribute__((ext_vector_type(4)));   // native vec for nontemporal builtin

// order-preserving float -> uint key (larger key <=> larger float)
__device__ __forceinline__ unsigned f2k(float f) {
    unsigned u = __float_as_uint(f);
    return (u & 0x80000000u) ? ~u : (u | 0x80000000u);
}

// Kernel 1: keys[n][p] = f2k(mean over c of x[n][c][p]), fp64 accumulation.
// Also emits a per-block byte-0 histogram of the final keys to histg[n][blk][256]
// (non-atomic 1 KiB store per block -> no global zero-init needed; the LDS atomics
// are wave-0-only and hide entirely under the memory-bound 128 MiB stream).
// 1024 blocks x 256 thr; __launch_bounds__(256,4) pins 4 waves/EU = 4 blocks/CU.
__global__ __launch_bounds__(256, 4) void col_mean_kernel(const float* __restrict__ x,
                                                          unsigned* __restrict__ keys_g,
                                                          unsigned* __restrict__ histg) {
    const int n     = blockIdx.x >> 6;            // 64 blocks per sample
    const int blk   = blockIdx.x & 63;
    const int pbase = blk << 6;                   // base p4-group of this block
    const int t     = threadIdx.x;
    const int p4    = pbase + (t & 63);
    const int cch   = t >> 6;                     // 0..3, channel chunk

    __shared__ unsigned hist[256];
    hist[t] = 0;                                  // all 256 threads, before first barrier

    const float4* xp = (const float4*)x + (size_t)n * C_ * 4096
                       + (size_t)cch * 32 * 4096 + p4;
    double s0 = 0.0, s1 = 0.0, s2 = 0.0, s3 = 0.0;
    #pragma unroll 8
    for (int cc = 0; cc < 32; ++cc) {
        float4 v = xp[(size_t)cc * 4096];
        s0 += (double)v.x; s1 += (double)v.y; s2 += (double)v.z; s3 += (double)v.w;
    }
    __shared__ double4 part[4][64];
    part[cch][t & 63] = make_double4(s0, s1, s2, s3);
    __syncthreads();
    if (t < 64) {
        double4 a = part[0][t], b = part[1][t], c = part[2][t], d = part[3][t];
        const double inv = 1.0 / (double)C_;
        uint4 r;
        r.x = f2k((float)((a.x + b.x + c.x + d.x) * inv));
        r.y = f2k((float)((a.y + b.y + c.y + d.y) * inv));
        r.z = f2k((float)((a.z + b.z + c.z + d.z) * inv));
        r.w = f2k((float)((a.w + b.w + c.w + d.w) * inv));
        ((uint4*)keys_g)[(size_t)n * 4096 + pbase + t] = r;
        atomicAdd(&hist[r.x >> 24], 1u);
        atomicAdd(&hist[r.y >> 24], 1u);
        atomicAdd(&hist[r.z >> 24], 1u);
        atomicAdd(&hist[r.w >> 24], 1u);
    }
    __syncthreads();
    histg[((size_t)n * 64 + blk) * 256 + t] = hist[t];
}

// Kernel 2: per-sample exact top-k threshold via 4-pass 256-bin radix select
// with keys held in registers (16/thread), then write per-column byte mask.
// Pass 0 histogram comes pre-reduced from kernel 1 (keys are means ~N(0, 1/128):
// byte-0 values collapse into a handful of exponent bins, so building that
// histogram here via LDS atomics serializes same-address lane-ops badly).
// Tie-break matches lax.top_k: among keys equal to threshold, lowest index wins.
__global__ __launch_bounds__(1024) void select_mask_kernel(const unsigned* __restrict__ keys_g,
                                                           const unsigned* __restrict__ histg,
                                                           unsigned char* __restrict__ mask) {
    __shared__ unsigned hist[256];
    __shared__ unsigned Sarr[257];
    __shared__ unsigned selb[2];
    __shared__ unsigned wsum[16];
    const int t    = threadIdx.x;
    const int lane = t & 63;
    const int wid  = t >> 6;
    const int n    = blockIdx.x;

    // thread t owns contiguous keys [t*16, t*16+16)  (index order preserved)
    unsigned kreg[16];
    {
        const uint4* kg = (const uint4*)(keys_g + (size_t)n * HW_);
        #pragma unroll
        for (int j = 0; j < 4; ++j) {
            uint4 v = kg[t * 4 + j];
            kreg[j * 4 + 0] = v.x; kreg[j * 4 + 1] = v.y;
            kreg[j * 4 + 2] = v.z; kreg[j * 4 + 3] = v.w;
        }
    }

    // pass-0 histogram: reduce the 64 per-block partials (L2-resident, no atomics)
    if (t < 256) {
        const unsigned* hg = histg + (size_t)n * 64 * 256 + t;
        unsigned s = 0;
        #pragma unroll 8
        for (int b = 0; b < 64; ++b) s += hg[b * 256];
        hist[t] = s;
    }
    __syncthreads();

    unsigned prefix = 0, need = K_;
    for (int pass = 0; pass < 4; ++pass) {
        const int shift = 24 - 8 * pass;
        if (pass > 0) {
            const unsigned himask = 0xFFFFFFFFu << (shift + 8);
            if (t < 256) hist[t] = 0;
            __syncthreads();
            #pragma unroll
            for (int j = 0; j < 16; ++j) {
                unsigned k = kreg[j];
                if (((k ^ prefix) & himask) == 0)
                    atomicAdd(&hist[(k >> shift) & 255], 1u);
            }
            __syncthreads();
        }
        if (wid == 0) {
            // wave 0: suffix sums over 256 bins; lane l owns bins [4l, 4l+4)
            unsigned h0 = hist[lane * 4], h1 = hist[lane * 4 + 1];
            unsigned h2 = hist[lane * 4 + 2], h3 = hist[lane * 4 + 3];
            unsigned s3 = h3, s2 = h2 + s3, s1 = h1 + s2, s0 = h0 + s1;
            unsigned run = s0;   // inclusive suffix of lane totals
            #pragma unroll
            for (int off = 1; off < 64; off <<= 1) {
                unsigned v = __shfl_down(run, off, 64);
                if (lane + off < 64) run += v;
            }
            unsigned after = run - s0;   // strictly-after total
            Sarr[lane * 4 + 0] = s0 + after;
            Sarr[lane * 4 + 1] = s1 + after;
            Sarr[lane * 4 + 2] = s2 + after;
            Sarr[lane * 4 + 3] = s3 + after;
            if (lane == 0) Sarr[256] = 0;
        }
        __syncthreads();
        if (t < 256) {
            if (Sarr[t] >= need && Sarr[t + 1] < need) {
                selb[0] = (unsigned)t;
                selb[1] = need - Sarr[t + 1];
            }
        }
        __syncthreads();
        prefix |= selb[0] << shift;
        need = selb[1];
        __syncthreads();
    }
    const unsigned thresh = prefix;   // exact k-th largest key
    const unsigned t_keep = need;     // # of ==thresh elements kept (lowest indices)

    // index-ordered rank among equals: wave shfl scan + cross-wave scan
    unsigned cnt = 0;
    #pragma unroll
    for (int j = 0; j < 16; ++j) cnt += (kreg[j] == thresh) ? 1u : 0u;
    unsigned inc = cnt;
    #pragma unroll
    for (int off = 1; off < 64; off <<= 1) {
        unsigned v = __shfl_up(inc, off, 64);
        if (lane >= off) inc += v;
    }
    if (lane == 63) wsum[wid] = inc;
    __syncthreads();
    if (t == 0) {
        unsigned acc = 0;
        #pragma unroll
        for (int i = 0; i < 16; ++i) { unsigned w = wsum[i]; wsum[i] = acc; acc += w; }
    }
    __syncthreads();
    const unsigned excl = wsum[wid] + inc - cnt;  // equals strictly before my chunk

    unsigned packed[4] = {0, 0, 0, 0};
    unsigned local = 0;
    #pragma unroll
    for (int j = 0; j < 16; ++j) {
        unsigned k = kreg[j];
        unsigned m;
        if (k > thresh) m = 1u;
        else if (k == thresh) { m = ((excl + local) < t_keep) ? 1u : 0u; ++local; }
        else m = 0u;
        packed[j >> 2] |= m << ((j & 3) * 8);
    }
    ((uint4*)(mask + (size_t)n * HW_))[t] = make_uint4(packed[0], packed[1], packed[2], packed[3]);
}

// Kernel 3: out[n][c][p] = mask ? x : x*(1-tau). Nontemporal stores keep x in L3
// (x is L3-resident from col_mean's read; out bypasses so it doesn't evict x).
__global__ __launch_bounds__(256) void apply_kernel(const float* __restrict__ x,
                                                    const unsigned char* __restrict__ mask,
                                                    const float* __restrict__ tau_p,
                                                    float* __restrict__ out) {
    int id = blockIdx.x * blockDim.x + threadIdx.x;   // float4 index
    int n  = id >> 19;                                // C_*HW_/4 = 2^19
    int p4 = id & 4095;                               // HW_/4
    const float s = 1.0f - *tau_p;
    float4 v = ((const float4*)x)[id];
    uchar4 m = ((const uchar4*)(mask + (size_t)n * HW_))[p4];
    nfloat4 r;
    r.x = m.x ? v.x : v.x * s;
    r.y = m.y ? v.y : v.y * s;
    r.z = m.z ? v.z : v.z * s;
    r.w = m.w ? v.w : v.w * s;
    __builtin_nontemporal_store(r, ((nfloat4*)out) + id);
}

extern "C" void kernel_launch(void* const* d_in, const int* in_sizes, int n_in,
                              void* d_out, int out_size, void* d_ws, size_t ws_size,
                              hipStream_t stream) {
    const float* x     = (const float*)d_in[0];
    const float* tau_p = (const float*)d_in[1];
    float* out = (float*)d_out;

    // ws layout: keys (1 MiB) | mask (256 KiB) | histg (1 MiB: [n][64 blocks][256 bins])
    char* ws = (char*)d_ws;
    unsigned*      keys  = (unsigned*)ws;
    unsigned char* mask  = (unsigned char*)(ws + (size_t)N_ * HW_ * sizeof(unsigned));
    unsigned*      histg = (unsigned*)(ws + (size_t)N_ * HW_ * sizeof(unsigned)
                                          + (size_t)N_ * HW_);

    col_mean_kernel<<<N_ * 64, 256, 0, stream>>>(x, keys, histg);
    select_mask_kernel<<<N_, 1024, 0, stream>>>(keys, histg, mask);
    apply_kernel<<<(N_ * C_ * HW_ / 4) / 256, 256, 0, stream>>>(x, mask, tau_p, out);
}